// Round 1
// baseline (15837.018 us; speedup 1.0000x reference)
//
#include <hip/hip_runtime.h>
#include <cstdint>
#include <cstddef>

#define LSEQ 8192
#define EDIM 256
#define HDM  256
#define G4   1024
#define NT   34
#define F_L2E 1.4426950408889634f
#define F_LN2 0.6931471805599453f

#if __has_builtin(__builtin_amdgcn_sdot4)
#define DOT4(a,b,c) __builtin_amdgcn_sdot4((a),(b),(c),false)
#else
__device__ __forceinline__ int dot4_fb(int a,int b,int c){
  c += (int)(signed char)(a & 0xff)        * (int)(signed char)(b & 0xff);
  c += (int)(signed char)((a>>8) & 0xff)   * (int)(signed char)((b>>8) & 0xff);
  c += (int)(signed char)((a>>16) & 0xff)  * (int)(signed char)((b>>16) & 0xff);
  c += (a>>24) * (b>>24);
  return c;
}
#define DOT4(a,b,c) dot4_fb((a),(b),(c))
#endif

__device__ __forceinline__ float sigf(float x){
  return __fdividef(1.f, 1.f + exp2f(-F_L2E * x));
}
__device__ __forceinline__ float tanhf_fast(float x){
  return 1.f - __fdividef(2.f, exp2f(2.f * F_L2E * x) + 1.f);
}

// ---------------------------------------------------------------------------
// Kernel 1: quantize Whh (both dirs) to int8 with per-row scale.
// grid 2048 x 64.  Wq layout: [dir][1024 rows][64 dwords], fac: [dir][1024]
// ---------------------------------------------------------------------------
__global__ void k_quant(const float* __restrict__ Whh_f,
                        const float* __restrict__ Whh_b,
                        int* __restrict__ Wq, float* __restrict__ fac){
  int bid = blockIdx.x;
  int dir = bid >> 10;
  int r   = bid & 1023;
  int i   = threadIdx.x;           // 0..63
  const float* W = (dir ? Whh_b : Whh_f) + r * 256 + i * 4;
  float w0 = W[0], w1 = W[1], w2 = W[2], w3 = W[3];
  float m = fmaxf(fmaxf(fabsf(w0), fabsf(w1)), fmaxf(fabsf(w2), fabsf(w3)));
  for (int s = 32; s; s >>= 1) m = fmaxf(m, __shfl_xor(m, s));
  float scale = (m > 0.f) ? m / 127.f : 1.f;
  float inv = __fdividef(1.f, scale);
  int q0 = (int)rintf(w0 * inv), q1 = (int)rintf(w1 * inv);
  int q2 = (int)rintf(w2 * inv), q3 = (int)rintf(w3 * inv);
  q0 = max(-127, min(127, q0)); q1 = max(-127, min(127, q1));
  q2 = max(-127, min(127, q2)); q3 = max(-127, min(127, q3));
  int p = (q0 & 255) | ((q1 & 255) << 8) | ((q2 & 255) << 16) | ((q3 & 255) << 24);
  Wq[(dir << 16) + (r << 6) + i] = p;
  if (i == 0) fac[(dir << 10) + r] = scale * (1.f / 127.f);
}

// ---------------------------------------------------------------------------
// Kernel 2: G[t][r] = b[r] + sum_e embed[words[t]][e] * Wih[r][e]
// grid (512, 2) x 256 threads; 16 timesteps per block.
// ---------------------------------------------------------------------------
__global__ void k_gproj(const int* __restrict__ words,
                        const float* __restrict__ embed,
                        const float* __restrict__ Wih_f, const float* __restrict__ b_f,
                        const float* __restrict__ Wih_b, const float* __restrict__ b_b,
                        float* __restrict__ G_f, float* __restrict__ G_b){
  int dir = blockIdx.y;
  const float* Wih = dir ? Wih_b : Wih_f;
  const float* bb  = dir ? b_b  : b_f;
  float* G = dir ? G_b : G_f;
  int t0 = blockIdx.x * 16;
  __shared__ __align__(16) float X[16 * 256];
  for (int idx = threadIdx.x; idx < 16 * 256; idx += 256) {
    int tt = idx >> 8, e = idx & 255;
    X[idx] = embed[(size_t)words[t0 + tt] * 256 + e];
  }
  __syncthreads();
  const float4* X4 = (const float4*)X;
  for (int rb = 0; rb < 4; rb++) {
    int r = rb * 256 + threadIdx.x;
    float bv = bb[r];
    float acc[16];
#pragma unroll
    for (int tt = 0; tt < 16; tt++) acc[tt] = bv;
    const float4* W4 = (const float4*)(Wih + (size_t)r * 256);
    for (int eb = 0; eb < 64; eb++) {
      float4 w = W4[eb];
#pragma unroll
      for (int tt = 0; tt < 16; tt++) {
        float4 x = X4[tt * 64 + eb];
        acc[tt] += w.x * x.x + w.y * x.y + w.z * x.z + w.w * x.w;
      }
    }
    for (int tt = 0; tt < 16; tt++)
      G[(size_t)(t0 + tt) * 1024 + r] = acc[tt];
  }
}

// ---------------------------------------------------------------------------
// Kernel 3: the two LSTM recurrences (block 0 = forward, block 1 = backward).
// 512 threads; thread t owns gate rows t and t+512 (int8, register-resident).
// ---------------------------------------------------------------------------
__global__ __launch_bounds__(512, 2) void k_lstm(const int* __restrict__ Wq,
                                                 const float* __restrict__ fac,
                                                 const float* __restrict__ G_f,
                                                 const float* __restrict__ G_b,
                                                 float* __restrict__ hf,
                                                 float* __restrict__ hb){
  int dir = blockIdx.x;
  const int4* Wq4 = (const int4*)(Wq + (dir << 16));
  const float* facp = fac + (dir << 10);
  const float* G = dir ? G_b : G_f;
  float* hout = dir ? hb : hf;
  int tid = threadIdx.x;

  __shared__ __align__(16) int h8[64];      // 256 int8 h values
  __shared__ float graw[1024];

  int4 wA[16], wB[16];
#pragma unroll
  for (int i = 0; i < 16; i++) {
    wA[i] = Wq4[tid * 16 + i];
    wB[i] = Wq4[(tid + 512) * 16 + i];
  }
  float fA = facp[tid], fB = facp[tid + 512];
  if (tid < 64) h8[tid] = 0;
  float c = 0.f;

  float ga0 = 0, ga1 = 0, ga2 = 0, ga3 = 0;
  float gb0 = 0, gb1 = 0, gb2 = 0, gb3 = 0;
  if (tid < 256) {
    int tm0 = dir ? 8191 : 0;
    int tm1 = dir ? 8190 : 1;
    const float* p0 = G + (size_t)tm0 * 1024 + tid;
    ga0 = p0[0]; ga1 = p0[256]; ga2 = p0[512]; ga3 = p0[768];
    const float* p1 = G + (size_t)tm1 * 1024 + tid;
    gb0 = p1[0]; gb1 = p1[256]; gb2 = p1[512]; gb3 = p1[768];
  }
  __syncthreads();

  auto step = [&](int t, float& g0, float& g1, float& g2, float& g3) {
    int accA = 0, accB = 0;
    const int4* h84 = (const int4*)h8;
#pragma unroll
    for (int i = 0; i < 16; ++i) {
      int4 hv = h84[i];
      accA = DOT4(wA[i].x, hv.x, accA); accA = DOT4(wA[i].y, hv.y, accA);
      accA = DOT4(wA[i].z, hv.z, accA); accA = DOT4(wA[i].w, hv.w, accA);
      accB = DOT4(wB[i].x, hv.x, accB); accB = DOT4(wB[i].y, hv.y, accB);
      accB = DOT4(wB[i].z, hv.z, accB); accB = DOT4(wB[i].w, hv.w, accB);
    }
    graw[tid]       = (float)accA * fA;
    graw[tid + 512] = (float)accB * fB;
    __syncthreads();
    if (tid < 256) {
      int time = dir ? (8191 - t) : t;
      float ri = graw[tid]       + g0;
      float rf = graw[256 + tid] + g1;
      float rg = graw[512 + tid] + g2;
      float ro = graw[768 + tid] + g3;
      float is = sigf(ri), fs = sigf(rf);
      float gt = tanhf_fast(rg), os = sigf(ro);
      c = fs * c + is * gt;
      float h = os * tanhf_fast(c);
      hout[(size_t)time * 256 + tid] = h;
      ((signed char*)h8)[tid] = (signed char)(int)rintf(h * 127.f);
      int tn = t + 2; if (tn > 8191) tn = 8191;
      int time2 = dir ? (8191 - tn) : tn;
      const float* p = G + (size_t)time2 * 1024 + tid;
      g0 = p[0]; g1 = p[256]; g2 = p[512]; g3 = p[768];
    }
    __syncthreads();
  };

  for (int t = 0; t < 8192; t += 2) {
    step(t,     ga0, ga1, ga2, ga3);
    step(t + 1, gb0, gb1, gb2, gb3);
  }
}

// ---------------------------------------------------------------------------
// Kernel 4: feats = [hf | hb] @ W_out.T + b_out.  grid 512 x 256.
// ---------------------------------------------------------------------------
__global__ void k_feats(const float* __restrict__ hf, const float* __restrict__ hb,
                        const float* __restrict__ W_out, const float* __restrict__ b_out,
                        float* __restrict__ feats){
  int t0 = blockIdx.x * 16;
  for (int oi = threadIdx.x; oi < 16 * NT; oi += 256) {
    int tt = oi / NT;
    int tag = oi - tt * NT;
    int t = t0 + tt;
    const float4* w4 = (const float4*)(W_out + (size_t)tag * 512);
    const float4* a4 = (const float4*)(hf + (size_t)t * 256);
    const float4* c4 = (const float4*)(hb + (size_t)t * 256);
    float acc = b_out[tag];
    for (int k = 0; k < 64; k++) {
      float4 w = w4[k]; float4 h = a4[k];
      acc += w.x * h.x + w.y * h.y + w.z * h.z + w.w * h.w;
    }
    for (int k = 0; k < 64; k++) {
      float4 w = w4[64 + k]; float4 h = c4[k];
      acc += w.x * h.x + w.y * h.y + w.z * h.z + w.w * h.w;
    }
    feats[(size_t)t * NT + tag] = acc;
  }
}

// ---------------------------------------------------------------------------
// Kernel 5: CRF scans. block 0 = alpha (forward), block 1 = beta (backward).
// 64 threads (1 wave), thread j owns tag j. log2-domain lse.
// ---------------------------------------------------------------------------
__global__ void k_crf(const float* __restrict__ feats, const float* __restrict__ trans,
                      float* __restrict__ wsA, float* __restrict__ wsB){
  int j = threadIdx.x;
  int jj = j < NT ? j : NT - 1;
  if (blockIdx.x == 0) {
    // ---- alpha ----
    __shared__ __align__(16) float aL[36];
    float trL[36];
#pragma unroll
    for (int i = 0; i < NT; i++) trL[i] = trans[jj * NT + i] * F_L2E;
    trL[34] = 0.f; trL[35] = 0.f;
    if (j < NT) aL[j] = (j == 32) ? 0.f : -10000.f * F_L2E;
    if (j == 0) { aL[34] = -1e30f; aL[35] = -1e30f; }
    __syncthreads();
    float fprev = feats[jj];
    for (int t = 0; t < LSEQ; t++) {
      int tn = (t + 1 < LSEQ) ? t + 1 : LSEQ - 1;
      float fnext = feats[(size_t)tn * NT + jj];
      float v[36];
      const float4* a4 = (const float4*)aL;
#pragma unroll
      for (int i2 = 0; i2 < 9; i2++) {
        float4 x = a4[i2];
        v[4*i2]   = x.x + trL[4*i2];
        v[4*i2+1] = x.y + trL[4*i2+1];
        v[4*i2+2] = x.z + trL[4*i2+2];
        v[4*i2+3] = x.w + trL[4*i2+3];
      }
      float m0 = -3e38f, m1 = -3e38f, m2 = -3e38f, m3 = -3e38f;
#pragma unroll
      for (int i = 0; i < 36; i += 4) {
        m0 = fmaxf(m0, v[i]);   m1 = fmaxf(m1, v[i+1]);
        m2 = fmaxf(m2, v[i+2]); m3 = fmaxf(m3, v[i+3]);
      }
      float m = fmaxf(fmaxf(m0, m1), fmaxf(m2, m3));
      float s0 = 0.f, s1 = 0.f, s2 = 0.f, s3 = 0.f;
#pragma unroll
      for (int i = 0; i < 36; i += 4) {
        s0 += exp2f(v[i]   - m); s1 += exp2f(v[i+1] - m);
        s2 += exp2f(v[i+2] - m); s3 += exp2f(v[i+3] - m);
      }
      float s = (s0 + s1) + (s2 + s3);
      float anew = m + __log2f(s) + fprev * F_L2E;   // scaled by log2(e)
      if (j < NT) wsA[(size_t)t * NT + j] = anew * F_LN2;
      __syncthreads();
      if (j < NT) aL[j] = anew;
      fprev = fnext;
      __syncthreads();
    }
  } else {
    // ---- beta ----
    __shared__ __align__(16) float uL[36];
    float tcL[36];
#pragma unroll
    for (int i = 0; i < NT; i++) tcL[i] = trans[i * NT + jj] * F_L2E;
    tcL[34] = 0.f; tcL[35] = 0.f;
    if (j == 0) { uL[34] = -1e30f; uL[35] = -1e30f; }
    // beta_last[j] = lse_i trans[i][j]
    float m = -3e38f;
#pragma unroll
    for (int i = 0; i < NT; i++) m = fmaxf(m, tcL[i]);
    float s = 0.f;
#pragma unroll
    for (int i = 0; i < NT; i++) s += exp2f(tcL[i] - m);
    float bL = m + __log2f(s);                        // scaled
    if (j < NT) wsB[(size_t)(LSEQ - 1) * NT + j] = bL * F_LN2;
    float fcur = feats[(size_t)(LSEQ - 1) * NT + jj]; // feat[t+1] for t = L-2
    __syncthreads();
    for (int t = LSEQ - 2; t >= 0; t--) {
      if (j < NT) uL[j] = bL + fcur * F_L2E;
      __syncthreads();
      int tp = (t > 0) ? t : 1;
      float fnext = feats[(size_t)tp * NT + jj];      // feat[t] for next iter
      float v[36];
      const float4* u4 = (const float4*)uL;
#pragma unroll
      for (int i2 = 0; i2 < 9; i2++) {
        float4 x = u4[i2];
        v[4*i2]   = x.x + tcL[4*i2];
        v[4*i2+1] = x.y + tcL[4*i2+1];
        v[4*i2+2] = x.z + tcL[4*i2+2];
        v[4*i2+3] = x.w + tcL[4*i2+3];
      }
      float m0 = -3e38f, m1 = -3e38f, m2 = -3e38f, m3 = -3e38f;
#pragma unroll
      for (int i = 0; i < 36; i += 4) {
        m0 = fmaxf(m0, v[i]);   m1 = fmaxf(m1, v[i+1]);
        m2 = fmaxf(m2, v[i+2]); m3 = fmaxf(m3, v[i+3]);
      }
      float mm = fmaxf(fmaxf(m0, m1), fmaxf(m2, m3));
      float s0 = 0.f, s1 = 0.f, s2 = 0.f, s3 = 0.f;
#pragma unroll
      for (int i = 0; i < 36; i += 4) {
        s0 += exp2f(v[i]   - mm); s1 += exp2f(v[i+1] - mm);
        s2 += exp2f(v[i+2] - mm); s3 += exp2f(v[i+3] - mm);
      }
      float ss = (s0 + s1) + (s2 + s3);
      bL = mm + __log2f(ss);
      if (j < NT) wsB[(size_t)t * NT + j] = bL * F_LN2;
      fcur = fnext;
      __syncthreads();
    }
  }
}

// ---------------------------------------------------------------------------
// Kernel 6: score = alpha + beta; tags = argmax.  grid 32 x 256.
// ---------------------------------------------------------------------------
__global__ void k_finish(const float* __restrict__ wsA, const float* __restrict__ wsB,
                         float* __restrict__ out){
  int t = blockIdx.x * 256 + threadIdx.x;
  float m = -3e38f; int bi = 0;
  for (int i = 0; i < NT; i++) {
    float sc = wsA[(size_t)t * NT + i] + wsB[(size_t)t * NT + i];
    out[(size_t)t * NT + i] = sc;
    if (sc > m) { m = sc; bi = i; }
  }
  out[(size_t)LSEQ * NT + t] = (float)bi;
}

// ---------------------------------------------------------------------------
extern "C" void kernel_launch(void* const* d_in, const int* in_sizes, int n_in,
                              void* d_out, int out_size, void* d_ws, size_t ws_size,
                              hipStream_t stream) {
  const int*   words  = (const int*)  d_in[0];
  const float* embed  = (const float*)d_in[1];
  const float* Wih_f  = (const float*)d_in[2];
  const float* Whh_f  = (const float*)d_in[3];
  const float* b_f    = (const float*)d_in[4];
  const float* Wih_b  = (const float*)d_in[5];
  const float* Whh_b  = (const float*)d_in[6];
  const float* b_b    = (const float*)d_in[7];
  const float* W_out  = (const float*)d_in[8];
  const float* b_out  = (const float*)d_in[9];
  const float* trans  = (const float*)d_in[10];
  float* out = (float*)d_out;

  float* wsf = (float*)d_ws;
  size_t off = 0;
  float* G_f   = wsf + off; off += (size_t)LSEQ * 1024;   // 8388608
  float* G_b   = wsf + off; off += (size_t)LSEQ * 1024;
  float* hf    = wsf + off; off += (size_t)LSEQ * 256;
  float* hb    = wsf + off; off += (size_t)LSEQ * 256;
  float* feats = wsf + off; off += (size_t)LSEQ * NT + 16;
  float* wsA   = wsf + off; off += (size_t)LSEQ * NT + 16;
  float* wsB   = wsf + off; off += (size_t)LSEQ * NT + 16;
  float* fac   = wsf + off; off += 2048;
  int*   Wq    = (int*)(wsf + off); off += 2 * 1024 * 64;

  k_quant<<<2048, 64, 0, stream>>>(Whh_f, Whh_b, Wq, fac);
  k_gproj<<<dim3(512, 2), 256, 0, stream>>>(words, embed, Wih_f, b_f, Wih_b, b_b, G_f, G_b);
  k_lstm<<<2, 512, 0, stream>>>(Wq, fac, G_f, G_b, hf, hb);
  k_feats<<<512, 256, 0, stream>>>(hf, hb, W_out, b_out, feats);
  k_crf<<<2, 64, 0, stream>>>(feats, trans, wsA, wsB);
  k_finish<<<32, 256, 0, stream>>>(wsA, wsB, out);
}

// Round 2
// 8582.973 us; speedup vs baseline: 1.8452x; 1.8452x over previous
//
#include <hip/hip_runtime.h>
#include <cstdint>
#include <cstddef>

#define LSEQ 8192
#define NT   34
#define NP   36
#define SCH  64
#define CCH  128
#define F_L2E 1.4426950408889634f
#define F_LN2 0.6931471805599453f

#if __has_builtin(__builtin_amdgcn_sdot4)
#define DOT4(a,b,c) __builtin_amdgcn_sdot4((a),(b),(c),false)
#else
__device__ __forceinline__ int dot4_fb(int a,int b,int c){
  c += (int)(signed char)(a & 0xff)        * (int)(signed char)(b & 0xff);
  c += (int)(signed char)((a>>8) & 0xff)   * (int)(signed char)((b>>8) & 0xff);
  c += (int)(signed char)((a>>16) & 0xff)  * (int)(signed char)((b>>16) & 0xff);
  c += (a>>24) * (b>>24);
  return c;
}
#define DOT4(a,b,c) dot4_fb((a),(b),(c))
#endif

__device__ __forceinline__ float ex2(float x){
#if __has_builtin(__builtin_amdgcn_exp2f)
  return __builtin_amdgcn_exp2f(x);
#else
  return exp2f(x);
#endif
}
__device__ __forceinline__ float lg2(float x){
#if __has_builtin(__builtin_amdgcn_logf)
  return __builtin_amdgcn_logf(x);   // v_log_f32 = log2
#else
  return __log2f(x);
#endif
}

__device__ __forceinline__ float sigf(float x){
  return __fdividef(1.f, 1.f + ex2(-F_L2E * x));
}
__device__ __forceinline__ float tanhf_fast(float x){
  return 1.f - __fdividef(2.f, ex2(2.f * F_L2E * x) + 1.f);
}

// barrier without the vmcnt(0) drain: LDS-only fence + s_barrier.
__device__ __forceinline__ void barrier_lds(){
  asm volatile("s_waitcnt lgkmcnt(0)\n\ts_barrier" ::: "memory");
}

// ---------------------------------------------------------------------------
// Kernel 1: quantize Whh (both dirs) to int8 with per-row scale.
// ---------------------------------------------------------------------------
__global__ void k_quant(const float* __restrict__ Whh_f,
                        const float* __restrict__ Whh_b,
                        int* __restrict__ Wq, float* __restrict__ fac){
  int bid = blockIdx.x;
  int dir = bid >> 10;
  int r   = bid & 1023;
  int i   = threadIdx.x;           // 0..63
  const float* W = (dir ? Whh_b : Whh_f) + r * 256 + i * 4;
  float w0 = W[0], w1 = W[1], w2 = W[2], w3 = W[3];
  float m = fmaxf(fmaxf(fabsf(w0), fabsf(w1)), fmaxf(fabsf(w2), fabsf(w3)));
  for (int s = 32; s; s >>= 1) m = fmaxf(m, __shfl_xor(m, s));
  float scale = (m > 0.f) ? m / 127.f : 1.f;
  float inv = __fdividef(1.f, scale);
  int q0 = (int)rintf(w0 * inv), q1 = (int)rintf(w1 * inv);
  int q2 = (int)rintf(w2 * inv), q3 = (int)rintf(w3 * inv);
  q0 = max(-127, min(127, q0)); q1 = max(-127, min(127, q1));
  q2 = max(-127, min(127, q2)); q3 = max(-127, min(127, q3));
  int p = (q0 & 255) | ((q1 & 255) << 8) | ((q2 & 255) << 16) | ((q3 & 255) << 24);
  Wq[(dir << 16) + (r << 6) + i] = p;
  if (i == 0) fac[(dir << 10) + r] = scale * (1.f / 127.f);
}

// ---------------------------------------------------------------------------
// Kernel 2: G[t][r] = b[r] + sum_e embed[words[t]][e] * Wih[r][e]
// ---------------------------------------------------------------------------
__global__ void k_gproj(const int* __restrict__ words,
                        const float* __restrict__ embed,
                        const float* __restrict__ Wih_f, const float* __restrict__ b_f,
                        const float* __restrict__ Wih_b, const float* __restrict__ b_b,
                        float* __restrict__ G_f, float* __restrict__ G_b){
  int dir = blockIdx.y;
  const float* Wih = dir ? Wih_b : Wih_f;
  const float* bb  = dir ? b_b  : b_f;
  float* G = dir ? G_b : G_f;
  int t0 = blockIdx.x * 16;
  __shared__ __align__(16) float X[16 * 256];
  for (int idx = threadIdx.x; idx < 16 * 256; idx += 256) {
    int tt = idx >> 8, e = idx & 255;
    X[idx] = embed[(size_t)words[t0 + tt] * 256 + e];
  }
  __syncthreads();
  const float4* X4 = (const float4*)X;
  for (int rb = 0; rb < 4; rb++) {
    int r = rb * 256 + threadIdx.x;
    float bv = bb[r];
    float acc[16];
#pragma unroll
    for (int tt = 0; tt < 16; tt++) acc[tt] = bv;
    const float4* W4 = (const float4*)(Wih + (size_t)r * 256);
    for (int eb = 0; eb < 64; eb++) {
      float4 w = W4[eb];
#pragma unroll
      for (int tt = 0; tt < 16; tt++) {
        float4 x = X4[tt * 64 + eb];
        acc[tt] += w.x * x.x + w.y * x.y + w.z * x.z + w.w * x.w;
      }
    }
    for (int tt = 0; tt < 16; tt++)
      G[(size_t)(t0 + tt) * 1024 + r] = acc[tt];
  }
}

// ---------------------------------------------------------------------------
// Kernel 3: LSTM recurrences. block 0 = forward, block 1 = backward.
// Prefetch issued at top of step (overlaps dot phase); raw barriers keep
// global loads/stores in flight across s_barrier (no vmcnt(0) drain).
// ---------------------------------------------------------------------------
__global__ __launch_bounds__(512, 2) void k_lstm(const int* __restrict__ Wq,
                                                 const float* __restrict__ fac,
                                                 const float* __restrict__ G_f,
                                                 const float* __restrict__ G_b,
                                                 float* __restrict__ hf,
                                                 float* __restrict__ hb){
  int dir = blockIdx.x;
  const int4* Wq4 = (const int4*)(Wq + (dir << 16));
  const float* facp = fac + (dir << 10);
  const float* G = dir ? G_b : G_f;
  float* hout = dir ? hb : hf;
  int tid = threadIdx.x;

  __shared__ __align__(16) int h8[64];      // 256 int8 h values
  __shared__ float graw[1024];

  int4 wA[16], wB[16];
#pragma unroll
  for (int i = 0; i < 16; i++) {
    wA[i] = Wq4[tid * 16 + i];
    wB[i] = Wq4[(tid + 512) * 16 + i];
  }
  float fA = facp[tid], fB = facp[tid + 512];
  if (tid < 64) h8[tid] = 0;
  float c = 0.f;

  float ga0 = 0, ga1 = 0, ga2 = 0, ga3 = 0;
  float gb0 = 0, gb1 = 0, gb2 = 0, gb3 = 0;
  if (tid < 256) {
    int tm0 = dir ? 8191 : 0;
    int tm1 = dir ? 8190 : 1;
    const float* p0 = G + (size_t)tm0 * 1024 + tid;
    ga0 = p0[0]; ga1 = p0[256]; ga2 = p0[512]; ga3 = p0[768];
    const float* p1 = G + (size_t)tm1 * 1024 + tid;
    gb0 = p1[0]; gb1 = p1[256]; gb2 = p1[512]; gb3 = p1[768];
  }
  __syncthreads();

  auto step = [&](int t, float& g0, float& g1, float& g2, float& g3) {
    // prefetch G for t+2 (same parity) -- issued before dots so the latency
    // overlaps the ~512-cycle dot phase.
    float pa0 = 0, pa1 = 0, pa2 = 0, pa3 = 0;
    if (tid < 256) {
      int tn = t + 2; if (tn > 8191) tn = 8191;
      int time2 = dir ? (8191 - tn) : tn;
      const float* p = G + (size_t)time2 * 1024 + tid;
      pa0 = p[0]; pa1 = p[256]; pa2 = p[512]; pa3 = p[768];
    }
    int accA = 0, accB = 0;
    const int4* h84 = (const int4*)h8;
#pragma unroll
    for (int i = 0; i < 16; ++i) {
      int4 hv = h84[i];
      accA = DOT4(wA[i].x, hv.x, accA); accA = DOT4(wA[i].y, hv.y, accA);
      accA = DOT4(wA[i].z, hv.z, accA); accA = DOT4(wA[i].w, hv.w, accA);
      accB = DOT4(wB[i].x, hv.x, accB); accB = DOT4(wB[i].y, hv.y, accB);
      accB = DOT4(wB[i].z, hv.z, accB); accB = DOT4(wB[i].w, hv.w, accB);
    }
    graw[tid]       = (float)accA * fA;
    graw[tid + 512] = (float)accB * fB;
    barrier_lds();
    if (tid < 256) {
      int time = dir ? (8191 - t) : t;
      float ri = graw[tid]       + g0;
      float rf = graw[256 + tid] + g1;
      float rg = graw[512 + tid] + g2;
      float ro = graw[768 + tid] + g3;
      float is = sigf(ri), fs = sigf(rf);
      float gt = tanhf_fast(rg), os = sigf(ro);
      c = fs * c + is * gt;
      float h = os * tanhf_fast(c);
      hout[(size_t)time * 256 + tid] = h;
      ((signed char*)h8)[tid] = (signed char)(int)rintf(h * 127.f);
    }
    g0 = pa0; g1 = pa1; g2 = pa2; g3 = pa3;   // waits vmcnt for prefetch here
    barrier_lds();
  };

  for (int t = 0; t < 8192; t += 2) {
    step(t,     ga0, ga1, ga2, ga3);
    step(t + 1, gb0, gb1, gb2, gb3);
  }
}

// ---------------------------------------------------------------------------
// Kernel 4: feats = [hf | hb] @ W_out.T + b_out.
// ---------------------------------------------------------------------------
__global__ void k_feats(const float* __restrict__ hf, const float* __restrict__ hb,
                        const float* __restrict__ W_out, const float* __restrict__ b_out,
                        float* __restrict__ feats){
  int t0 = blockIdx.x * 16;
  for (int oi = threadIdx.x; oi < 16 * NT; oi += 256) {
    int tt = oi / NT;
    int tag = oi - tt * NT;
    int t = t0 + tt;
    const float4* w4 = (const float4*)(W_out + (size_t)tag * 512);
    const float4* a4 = (const float4*)(hf + (size_t)t * 256);
    const float4* c4 = (const float4*)(hb + (size_t)t * 256);
    float acc = b_out[tag];
    for (int k = 0; k < 64; k++) {
      float4 w = w4[k]; float4 h = a4[k];
      acc += w.x * h.x + w.y * h.y + w.z * h.z + w.w * h.w;
    }
    for (int k = 0; k < 64; k++) {
      float4 w = w4[64 + k]; float4 h = c4[k];
      acc += w.x * h.x + w.y * h.y + w.z * h.z + w.w * h.w;
    }
    feats[(size_t)t * NT + tag] = acc;
  }
}

// ---------------------------------------------------------------------------
// CRF as a chunked associative scan in the (lse,+) semiring, log2-domain.
// alpha: M_t[j][i] = λ(tr[j][i] + feat_t[j]);  alpha_t = M_t ⊗ alpha_{t-1}
// beta : N_t[j][i] = λ(tr[i][j] + feat_{t+1}[i]); beta_t = N_t ⊗ beta_{t+1},
//        N_{L-1} = identity, virtual beta_L[j] = lse_i λ tr[i][j].
// Phase 1: per-chunk matrix products (128 chunks x 2 dirs, parallel).
// Phase 2: sequential matvec prefix over 128 chunk products (2 blocks).
// Phase 3: per-chunk vector re-scan emitting wsA/wsB (parallel).
// ---------------------------------------------------------------------------
__global__ __launch_bounds__(320) void k_crf_p1(const float* __restrict__ feats,
                                                const float* __restrict__ trans,
                                                float* __restrict__ Pg,
                                                float* __restrict__ rmaxG){
  int dir = blockIdx.x >> 7;
  int c   = blockIdx.x & (CCH - 1);
  int tid = threadIdx.x;
  int t0  = c * SCH;

  __shared__ __align__(16) float TRM[NT * NP];
  __shared__ float Fe[(SCH + 1) * NT];
  __shared__ __align__(16) float Pbuf[2][NT * NP];
  __shared__ float CM[NP];
  __shared__ float RMs[NT];

  for (int idx = tid; idx < NT * NT; idx += 320) {
    int j = idx / NT, k = idx - j * NT;
    float v = (dir == 0) ? trans[j * NT + k] : trans[k * NT + j];
    TRM[j * NP + k] = v * F_L2E;
  }
  for (int idx = tid; idx < (SCH + 1) * NT; idx += 320) {
    int s = idx / NT, j = idx - s * NT;
    int t = t0 + s; if (t > LSEQ - 1) t = LSEQ - 1;
    Fe[idx] = feats[(size_t)t * NT + j] * F_L2E;
  }
  for (int idx = tid; idx < NT * NP; idx += 320) {
    int k = idx / NP, i = idx - k * NP;
    Pbuf[0][idx] = (i < NT && i == k) ? 0.f : -1e30f;
  }
  if (tid < NP) CM[tid] = (tid < NT) ? 0.f : -1e30f;
  __syncthreads();
  if (tid < NT) {
    float m = -3e38f;
    for (int k = 0; k < NT; k++) m = fmaxf(m, TRM[tid * NP + k]);
    RMs[tid] = m;
  }
  __syncthreads();
  for (int idx = tid; idx < NT * NT; idx += 320) {
    int j = idx / NT, k = idx - j * NT;
    TRM[j * NP + k] -= RMs[j];
  }
  __syncthreads();

  int cur = 0;
  int j = tid / 9, g = tid - (tid / 9) * 9;
  bool act = (tid < 306);
  int i0 = 4 * g;

  for (int s = 0; s < SCH; s++) {
    int t = (dir == 0) ? (t0 + s) : (t0 + SCH - 1 - s);
    if (dir == 1 && t == LSEQ - 1) continue;   // identity factor at t=L-1
    const float* Pc = Pbuf[cur];
    float* Pn = Pbuf[cur ^ 1];
    if (act) {
      float cm0 = CM[i0], cm1 = CM[i0 + 1], cm2 = CM[i0 + 2], cm3 = CM[i0 + 3];
      float s0 = 0, s1 = 0, s2 = 0, s3 = 0;
      const float* trp = TRM + j * NP;
      const float* fep = Fe + (t + 1 - t0) * NT;   // only read when dir==1
#pragma unroll
      for (int k = 0; k < NT; k++) {
        float trv = trp[k];
        if (dir == 1) trv += fep[k];
        float4 p = *(const float4*)&Pc[k * NP + i0];
        s0 += ex2(trv + p.x - cm0);
        s1 += ex2(trv + p.y - cm1);
        s2 += ex2(trv + p.z - cm2);
        s3 += ex2(trv + p.w - cm3);
      }
      float base = RMs[j] + ((dir == 0) ? Fe[(t - t0) * NT + j] : 0.f);
      float4 o;
      o.x = base + cm0 + lg2(s0);
      o.y = base + cm1 + lg2(s1);
      o.z = (i0 + 2 < NT) ? (base + cm2 + lg2(s2)) : -1e30f;
      o.w = (i0 + 3 < NT) ? (base + cm3 + lg2(s3)) : -1e30f;
      *(float4*)&Pn[j * NP + i0] = o;
    }
    __syncthreads();
    if (tid < NP) {
      float m = -3e38f;
      const float* col = Pn + tid;
      for (int k = 0; k < NT; k++) m = fmaxf(m, col[k * NP]);
      CM[tid] = m;
    }
    cur ^= 1;
    __syncthreads();
  }

  const float* Pf = Pbuf[cur];
  size_t base = (size_t)((dir << 7) + c) * (NT * NP);
  for (int idx = tid; idx < NT * NP; idx += 320)
    Pg[base + idx] = Pf[idx];
  if (tid < NT) {
    float m = -3e38f;
    for (int i = 0; i < NT; i++) m = fmaxf(m, Pf[tid * NP + i]);
    rmaxG[((dir << 7) + c) * NT + tid] = m;
  }
}

__global__ void k_crf_p2(const float* __restrict__ trans,
                         const float* __restrict__ Pg,
                         const float* __restrict__ rmaxG,
                         float* __restrict__ vIn){
  int dir = blockIdx.x;
  int lane = threadIdx.x;           // 64, single wave
  bool a = (lane < NT);
  int j = a ? lane : 0;
  __shared__ float V[NP];

  float v;
  if (dir == 0) {
    v = (lane == 32) ? 0.f : -10000.f * F_L2E;
  } else {
    float m = -3e38f;
    for (int i = 0; i < NT; i++) m = fmaxf(m, trans[i * NT + j]);
    float s = 0.f;
    for (int i = 0; i < NT; i++) s += ex2((trans[i * NT + j] - m) * F_L2E);
    v = m * F_L2E + lg2(s);
  }
  if (lane < NP) V[lane] = -1e30f;
  barrier_lds();
  if (a) V[j] = v;
  barrier_lds();
  float vm = a ? v : -3e38f;
  for (int off = 32; off; off >>= 1) vm = fmaxf(vm, __shfl_xor(vm, off));

  if (a) {
    int c0 = (dir == 0) ? 0 : (CCH - 1);
    vIn[((size_t)(dir << 7) + c0) * NP + j] = v;
  }

  for (int it = 0; it < CCH - 1; it++) {
    int c = (dir == 0) ? it : (CCH - 1 - it);
    const float* row = Pg + ((size_t)(dir << 7) + c) * (NT * NP) + j * NP;
    float rm = rmaxG[((dir << 7) + c) * NT + j];
    float m = rm + vm;
    float s = 0.f;
#pragma unroll
    for (int k = 0; k < NP; k += 4) {
      float4 p = *(const float4*)&row[k];
      s += ex2(p.x + V[k]     - m);
      s += ex2(p.y + V[k + 1] - m);
      s += ex2(p.z + V[k + 2] - m);
      s += ex2(p.w + V[k + 3] - m);
    }
    float nv = m + lg2(s);
    if (a) V[j] = nv;
    barrier_lds();
    float x = a ? nv : -3e38f;
    for (int off = 32; off; off >>= 1) x = fmaxf(x, __shfl_xor(x, off));
    vm = x;
    int cn = (dir == 0) ? (c + 1) : (c - 1);
    if (a) vIn[((size_t)(dir << 7) + cn) * NP + j] = nv;
  }
}

__global__ void k_crf_p3(const float* __restrict__ feats,
                         const float* __restrict__ trans,
                         const float* __restrict__ vIn,
                         float* __restrict__ wsA,
                         float* __restrict__ wsB){
  int dir = blockIdx.x >> 7;
  int c   = blockIdx.x & (CCH - 1);
  int lane = threadIdx.x;           // 64, single wave
  int t0 = c * SCH;
  bool a = (lane < NT);
  int j = a ? lane : 0;
  __shared__ float A[NP];
  __shared__ float U[NP];

  float trr[NT];
  float rm = -3e38f;
#pragma unroll
  for (int k = 0; k < NT; k++) {
    float vv = (dir == 0) ? trans[j * NT + k] : trans[k * NT + j];
    trr[k] = vv * F_L2E;
    rm = fmaxf(rm, trr[k]);
  }
  if (lane < NP) { A[lane] = -1e30f; U[lane] = -1e30f; }
  float v0 = vIn[((size_t)(dir << 7) + c) * NP + j];
  barrier_lds();
  if (a) A[j] = v0;
  barrier_lds();
  float am = a ? v0 : -3e38f;
  for (int off = 32; off; off >>= 1) am = fmaxf(am, __shfl_xor(am, off));

  if (dir == 0) {
    float fe = feats[(size_t)t0 * NT + j] * F_L2E;
    for (int s = 0; s < SCH; s++) {
      int t = t0 + s;
      int tn = (t + 1 < LSEQ) ? t + 1 : LSEQ - 1;
      float fe_n = feats[(size_t)tn * NT + j] * F_L2E;
      float m = rm + am;
      float ss = 0.f;
#pragma unroll
      for (int k = 0; k < NT; k++) ss += ex2(trr[k] + A[k] - m);
      float out = m + lg2(ss) + fe;
      if (a) wsA[(size_t)t * NT + j] = out * F_LN2;
      if (a) A[j] = out;
      barrier_lds();
      float x = a ? out : -3e38f;
      for (int off = 32; off; off >>= 1) x = fmaxf(x, __shfl_xor(x, off));
      am = x;
      fe = fe_n;
    }
  } else {
    float b = v0;                    // beta_{t+1}, per-lane register
    int tfirst = t0 + SCH; if (tfirst > LSEQ - 1) tfirst = LSEQ - 1;
    float fe = feats[(size_t)tfirst * NT + j] * F_L2E;   // feat_{t+1} for first step
    for (int s = 0; s < SCH; s++) {
      int t = t0 + SCH - 1 - s;
      float fe_n = feats[(size_t)t * NT + j] * F_L2E;    // next step's feat_{t+1}
      float out;
      if (t == LSEQ - 1) {
        out = b;                     // identity factor
      } else {
        if (a) U[j] = b + fe;
        barrier_lds();
        float um = a ? U[j] : -3e38f;
        for (int off = 32; off; off >>= 1) um = fmaxf(um, __shfl_xor(um, off));
        float m = rm + um;
        float ss = 0.f;
#pragma unroll
        for (int k = 0; k < NT; k++) ss += ex2(trr[k] + U[k] - m);
        out = m + lg2(ss);
        barrier_lds();
      }
      if (a) wsB[(size_t)t * NT + j] = out * F_LN2;
      b = out;
      fe = fe_n;
    }
  }
}

// ---------------------------------------------------------------------------
// Kernel: score = alpha + beta; tags = argmax.
// ---------------------------------------------------------------------------
__global__ void k_finish(const float* __restrict__ wsA, const float* __restrict__ wsB,
                         float* __restrict__ out){
  int t = blockIdx.x * 256 + threadIdx.x;
  float m = -3e38f; int bi = 0;
  for (int i = 0; i < NT; i++) {
    float sc = wsA[(size_t)t * NT + i] + wsB[(size_t)t * NT + i];
    out[(size_t)t * NT + i] = sc;
    if (sc > m) { m = sc; bi = i; }
  }
  out[(size_t)LSEQ * NT + t] = (float)bi;
}

// ---------------------------------------------------------------------------
extern "C" void kernel_launch(void* const* d_in, const int* in_sizes, int n_in,
                              void* d_out, int out_size, void* d_ws, size_t ws_size,
                              hipStream_t stream) {
  const int*   words  = (const int*)  d_in[0];
  const float* embed  = (const float*)d_in[1];
  const float* Wih_f  = (const float*)d_in[2];
  const float* Whh_f  = (const float*)d_in[3];
  const float* b_f    = (const float*)d_in[4];
  const float* Wih_b  = (const float*)d_in[5];
  const float* Whh_b  = (const float*)d_in[6];
  const float* b_b    = (const float*)d_in[7];
  const float* W_out  = (const float*)d_in[8];
  const float* b_out  = (const float*)d_in[9];
  const float* trans  = (const float*)d_in[10];
  float* out = (float*)d_out;

  float* wsf = (float*)d_ws;
  size_t off = 0;
  float* G_f   = wsf + off; off += (size_t)LSEQ * 1024;
  float* G_b   = wsf + off; off += (size_t)LSEQ * 1024;
  float* hf    = wsf + off; off += (size_t)LSEQ * 256;
  float* hb    = wsf + off; off += (size_t)LSEQ * 256;
  float* feats = wsf + off; off += (size_t)LSEQ * NT + 16;
  float* wsA   = wsf + off; off += (size_t)LSEQ * NT + 16;
  float* wsB   = wsf + off; off += (size_t)LSEQ * NT + 16;
  float* fac   = wsf + off; off += 2048;
  int*   Wq    = (int*)(wsf + off); off += 2 * 1024 * 64;
  // CRF scan scratch overlaps G_f (dead after k_lstm)
  float* Pg    = G_f;                                   // 256 * 34*36
  float* rmaxG = G_f + 256 * (NT * NP);                 // 256 * 34
  float* vIn   = rmaxG + 256 * NT + 32;                 // 256 * 36

  k_quant<<<2048, 64, 0, stream>>>(Whh_f, Whh_b, Wq, fac);
  k_gproj<<<dim3(512, 2), 256, 0, stream>>>(words, embed, Wih_f, b_f, Wih_b, b_b, G_f, G_b);
  k_lstm<<<2, 512, 0, stream>>>(Wq, fac, G_f, G_b, hf, hb);
  k_feats<<<512, 256, 0, stream>>>(hf, hb, W_out, b_out, feats);
  k_crf_p1<<<256, 320, 0, stream>>>(feats, trans, Pg, rmaxG);
  k_crf_p2<<<2, 64, 0, stream>>>(trans, Pg, rmaxG, vIn);
  k_crf_p3<<<256, 64, 0, stream>>>(feats, trans, vIn, wsA, wsB);
  k_finish<<<32, 256, 0, stream>>>(wsA, wsB, out);
}